// Round 11
// baseline (546.844 us; speedup 1.0000x reference)
//
#include <hip/hip_runtime.h>

// VectorQuantizer: x[16384][64] fp32, codebook[8192][64] fp32
// out = concat(discrete one-hot [16384][8192] fp32, quantized [16384][64] fp32)
// argmin_k ||x-c_k||^2 == argmax_k (x.c_k - 0.5||c_k||^2)
//
// r10 -> r11: raise arithmetic intensity per B-load. 64 rows/block (4 rowgroups),
// 512-thread blocks (8 waves x 1024 codes): 32 MFMAs per 4 B-frag loads (2x r10),
// per-CU packed-codebook traffic halved (2 MB). Register prefetch depth 1;
// NT zero-fill interleaved (proven free under compute); in-block final argmax.
// Exact fp32 dots via fp16 hi/lo split, 8 MFMA terms, bit-identical order.

#define NROWS 16384
#define KCODES 8192
#define DDIM 64
#define RPB 64                    // rows per block (4 rowgroups of 16)
#define CWAVES 8                  // waves per block (512 threads)
#define WCODES (KCODES / CWAVES)  // 1024 codes per wave
#define WTILES (WCODES / 16)      // 64 tiles per wave

typedef float    f32x4 __attribute__((ext_vector_type(4)));
typedef _Float16 f16x8 __attribute__((ext_vector_type(8)));

// ---------------- kernel 0: fused pack + cn2 ----------------
// thread (Tg, L): code = Tg*16 + (L&15), k-slice = (L>>4)*8 (+32).
// packed[Tg][frag][lane]: frag 0=hi k0..31, 1=hi k32..63, 2=lo k0..31, 3=lo k32..63.
__global__ __launch_bounds__(256) void k_prep(const float* __restrict__ cb,
                                              f16x8* __restrict__ packed,
                                              float* __restrict__ cn2) {
    int tid = blockIdx.x * 256 + threadIdx.x;   // 0..32767
    int Tg = tid >> 6, L = tid & 63;
    int lane15 = L & 15, quad = L >> 4;
    int code = Tg * 16 + lane15;
    const float* p = cb + (size_t)code * DDIM + quad * 8;
    f16x8 h0, l0, h1, l1;
    float s = 0.f;
#pragma unroll
    for (int j = 0; j < 8; ++j) {
        float v = p[j];
        _Float16 h = (_Float16)v;
        h0[j] = h; l0[j] = (_Float16)(v - (float)h);
        s = fmaf(v, v, s);
        float w = p[32 + j];
        _Float16 h2 = (_Float16)w;
        h1[j] = h2; l1[j] = (_Float16)(w - (float)h2);
        s = fmaf(w, w, s);
    }
    s += __shfl_xor(s, 16, 64);
    s += __shfl_xor(s, 32, 64);
    if (quad == 0) cn2[code] = 0.5f * s;
    f16x8* out = packed + (size_t)Tg * 256 + L;
    out[0]   = h0;
    out[64]  = h1;
    out[128] = l0;
    out[192] = l1;
}

// ---------------- kernel 1: main MFMA + argmax + NT zero-fill + one-hot ----------------
__global__ __launch_bounds__(512, 2) void k_main(const float* __restrict__ x,
                                                 const f16x8* __restrict__ packed,
                                                 const float* __restrict__ cn2,
                                                 float* __restrict__ discrete,
                                                 int* __restrict__ bestidx) {
    const int t = threadIdx.x;
    const int L = t & 63;
    const int w = t >> 6;                 // wave = code eighth (ascending codes)
    const int row0 = blockIdx.x * RPB;
    const int lane15 = L & 15;
    const int quad = L >> 4;

    // ---- A fragments: 4 rowgroups, exact hi/lo split ----
    f16x8 Xh0[4], Xh1[4], Xl0[4], Xl1[4];
#pragma unroll
    for (int rg = 0; rg < 4; ++rg) {
        const float* xp = x + (size_t)(row0 + rg * 16 + lane15) * DDIM + quad * 8;
#pragma unroll
        for (int j = 0; j < 8; ++j) {
            float v = xp[j];        _Float16 h = (_Float16)v;
            Xh0[rg][j] = h; Xl0[rg][j] = (_Float16)(v - (float)h);
            v = xp[32 + j];         h = (_Float16)v;
            Xh1[rg][j] = h; Xl1[rg][j] = (_Float16)(v - (float)h);
        }
    }

    float bv[4][4];
    int   bi[4][4];
#pragma unroll
    for (int rg = 0; rg < 4; ++rg)
#pragma unroll
        for (int r = 0; r < 4; ++r) { bv[rg][r] = -3.4e38f; bi[rg][r] = 0; }

    const f32x4 zero4 = {0.f, 0.f, 0.f, 0.f};
    const int code0 = w * WCODES;
    const f16x8* pb = packed + (size_t)(code0 >> 4) * 256 + L;

    // preload tile 0 (B frags + cn)
    f16x8 ch0 = pb[0], ch1 = pb[64], cl0 = pb[128], cl1 = pb[192];
    float cn = cn2[code0 + lane15];
    f32x4* zdst = (f32x4*)(discrete + (size_t)row0 * KCODES);   // 131072 f32x4/block

    for (int i = 0; i < WTILES; ++i) {
        // ---- prefetch tile i+1 (stays in flight under the 32-MFMA burst) ----
        const int inext = (i + 1 < WTILES) ? i + 1 : i;
        const f16x8* pn = packed + (size_t)((code0 >> 4) + inext) * 256 + L;
        f16x8 n0 = pn[0], n1 = pn[64], n2 = pn[128], n3 = pn[192];
        float cnn = cn2[code0 + inext * 16 + lane15];

        // ---- NT zero-fill: 4 f32x4 per thread per tile (131072 total/block) ----
        {
            int g = i * 2048 + t;
            __builtin_nontemporal_store(zero4, zdst + g);
            __builtin_nontemporal_store(zero4, zdst + g + 512);
            __builtin_nontemporal_store(zero4, zdst + g + 1024);
            __builtin_nontemporal_store(zero4, zdst + g + 1536);
        }

        // ---- compute current tile: 4 rowgroups x 8 terms ----
        const int ct = code0 + i * 16;
        f32x4 acc[4];
#pragma unroll
        for (int rg = 0; rg < 4; ++rg) acc[rg] = (f32x4){-cn, -cn, -cn, -cn};

#pragma unroll
        for (int rg = 0; rg < 4; ++rg) acc[rg] = __builtin_amdgcn_mfma_f32_16x16x32_f16(Xh0[rg], ch0, acc[rg], 0, 0, 0);
#pragma unroll
        for (int rg = 0; rg < 4; ++rg) acc[rg] = __builtin_amdgcn_mfma_f32_16x16x32_f16(Xh1[rg], ch1, acc[rg], 0, 0, 0);
#pragma unroll
        for (int rg = 0; rg < 4; ++rg) acc[rg] = __builtin_amdgcn_mfma_f32_16x16x32_f16(Xl0[rg], ch0, acc[rg], 0, 0, 0);
#pragma unroll
        for (int rg = 0; rg < 4; ++rg) acc[rg] = __builtin_amdgcn_mfma_f32_16x16x32_f16(Xl1[rg], ch1, acc[rg], 0, 0, 0);
#pragma unroll
        for (int rg = 0; rg < 4; ++rg) acc[rg] = __builtin_amdgcn_mfma_f32_16x16x32_f16(Xh0[rg], cl0, acc[rg], 0, 0, 0);
#pragma unroll
        for (int rg = 0; rg < 4; ++rg) acc[rg] = __builtin_amdgcn_mfma_f32_16x16x32_f16(Xh1[rg], cl1, acc[rg], 0, 0, 0);
#pragma unroll
        for (int rg = 0; rg < 4; ++rg) acc[rg] = __builtin_amdgcn_mfma_f32_16x16x32_f16(Xl0[rg], cl0, acc[rg], 0, 0, 0);
#pragma unroll
        for (int rg = 0; rg < 4; ++rg) acc[rg] = __builtin_amdgcn_mfma_f32_16x16x32_f16(Xl1[rg], cl1, acc[rg], 0, 0, 0);

        const int vcode = ct + lane15;
#pragma unroll
        for (int rg = 0; rg < 4; ++rg)
#pragma unroll
            for (int r = 0; r < 4; ++r)
                if (acc[rg][r] > bv[rg][r]) { bv[rg][r] = acc[rg][r]; bi[rg][r] = vcode; }

        ch0 = n0; ch1 = n1; cl0 = n2; cl1 = n3; cn = cnn;
    }

    // ---- 16-lane butterfly per quad, then cross-wave LDS reduce ----
    __shared__ float rv[RPB][CWAVES + 1];
    __shared__ int   ri[RPB][CWAVES + 1];
#pragma unroll
    for (int rg = 0; rg < 4; ++rg) {
#pragma unroll
        for (int r = 0; r < 4; ++r) {
            float v = bv[rg][r];
            int  id = bi[rg][r];
#pragma unroll
            for (int m = 1; m < 16; m <<= 1) {
                float ov = __shfl_xor(v, m, 64); int oi = __shfl_xor(id, m, 64);
                if (ov > v || (ov == v && oi < id)) { v = ov; id = oi; }
            }
            if (lane15 == 0) {
                rv[rg * 16 + quad * 4 + r][w] = v;
                ri[rg * 16 + quad * 4 + r][w] = id;
            }
        }
    }
    __syncthreads();   // drains NT zero stores before the 1.0 write
    if (t < RPB) {
        float bvf = rv[t][0];
        int   bif = ri[t][0];
#pragma unroll
        for (int w2 = 1; w2 < CWAVES; ++w2) {  // ascending wave = ascending codes
            float v = rv[t][w2];
            int  id = ri[t][w2];
            if (v > bvf || (v == bvf && id < bif)) { bvf = v; bif = id; }
        }
        int row = row0 + t;
        bestidx[row] = bif;
        discrete[(size_t)row * KCODES + bif] = 1.0f;
    }
}

// ---------------- kernel 2: quantized gather ----------------
__global__ __launch_bounds__(256) void k_finish(const float* __restrict__ cb,
                                                const int* __restrict__ bestidx,
                                                float* __restrict__ quantized) {
    __shared__ int sidx[256];
    const int t = threadIdx.x;
    const int row0 = blockIdx.x * 256;
    sidx[t] = bestidx[row0 + t];
    __syncthreads();
#pragma unroll
    for (int i = 0; i < 16; ++i) {
        int e = i * 256 + t;
        int r = e >> 4, c = e & 15;
        float4 v = *((const float4*)(cb + (size_t)sidx[r] * DDIM) + c);
        *((float4*)(quantized + (size_t)(row0 + r) * DDIM) + c) = v;
    }
}

extern "C" void kernel_launch(void* const* d_in, const int* in_sizes, int n_in,
                              void* d_out, int out_size, void* d_ws, size_t ws_size,
                              hipStream_t stream) {
    const float* x  = (const float*)d_in[0];   // 16*32*32*64
    const float* cb = (const float*)d_in[1];   // 8192*64

    float* discrete  = (float*)d_out;                          // 16384*8192
    float* quantized = (float*)d_out + (size_t)NROWS * KCODES; // 16384*64

    // packed B-fragments (2 MB) live in the quantized output region (4 MB):
    // k_main only reads it; k_finish overwrites quantized afterwards.
    f16x8* packed = (f16x8*)quantized;

    float* cn2     = (float*)d_ws;             // 8192 floats
    int*   bestidx = (int*)(cn2 + KCODES);     // 16384 ints

    k_prep<<<(KCODES / 16) * 64 / 256, 256, 0, stream>>>(cb, packed, cn2);
    k_main<<<NROWS / RPB, CWAVES * 64, 0, stream>>>(x, packed, cn2, discrete, bestidx);
    k_finish<<<NROWS / 256, 256, 0, stream>>>(cb, bestidx, quantized);
}

// Round 12
// 530.987 us; speedup vs baseline: 1.0299x; 1.0299x over previous
//
#include <hip/hip_runtime.h>

// VectorQuantizer: x[16384][64] fp32, codebook[8192][64] fp32
// out = concat(discrete one-hot [16384][8192] fp32, quantized [16384][64] fp32)
// argmin_k ||x-c_k||^2 == argmax_k (x.c_k - 0.5||c_k||^2)
//
// r11 -> r12: r10 structure (RPB=32, 4 waves x 2048 codes, 256thr, 16 waves/CU)
// with DEPTH-2 register prefetch: B-frags + cn2 for tile i+2 issued each iter,
// reach ~470cyc > loaded-L2 latency, so the per-tile entry stall disappears.
// __launch_bounds__(256,4) holds the 128-VGPR cap (≈124 needed).
// Exact fp32 dots via fp16 hi/lo split, 8 MFMA terms, bit-identical order.

#define NROWS 16384
#define KCODES 8192
#define DDIM 64
#define RPB 32                    // rows per block
#define CWAVES 4                  // waves per block (256 threads)
#define WCODES (KCODES / CWAVES)  // 2048 codes per wave
#define WTILES (WCODES / 16)      // 128 tiles per wave

typedef float    f32x4 __attribute__((ext_vector_type(4)));
typedef _Float16 f16x8 __attribute__((ext_vector_type(8)));

// ---------------- kernel 0: fused pack + cn2 ----------------
// thread (Tg, L): code = Tg*16 + (L&15), k-slice = (L>>4)*8 (+32).
// packed[Tg][frag][lane]: frag 0=hi k0..31, 1=hi k32..63, 2=lo k0..31, 3=lo k32..63.
__global__ __launch_bounds__(256) void k_prep(const float* __restrict__ cb,
                                              f16x8* __restrict__ packed,
                                              float* __restrict__ cn2) {
    int tid = blockIdx.x * 256 + threadIdx.x;   // 0..32767
    int Tg = tid >> 6, L = tid & 63;
    int lane15 = L & 15, quad = L >> 4;
    int code = Tg * 16 + lane15;
    const float* p = cb + (size_t)code * DDIM + quad * 8;
    f16x8 h0, l0, h1, l1;
    float s = 0.f;
#pragma unroll
    for (int j = 0; j < 8; ++j) {
        float v = p[j];
        _Float16 h = (_Float16)v;
        h0[j] = h; l0[j] = (_Float16)(v - (float)h);
        s = fmaf(v, v, s);
        float w = p[32 + j];
        _Float16 h2 = (_Float16)w;
        h1[j] = h2; l1[j] = (_Float16)(w - (float)h2);
        s = fmaf(w, w, s);
    }
    s += __shfl_xor(s, 16, 64);
    s += __shfl_xor(s, 32, 64);
    if (quad == 0) cn2[code] = 0.5f * s;
    f16x8* out = packed + (size_t)Tg * 256 + L;
    out[0]   = h0;
    out[64]  = h1;
    out[128] = l0;
    out[192] = l1;
}

// ---------------- kernel 1: main MFMA + argmax + NT zero-fill + one-hot ----------------
__global__ __launch_bounds__(256, 4) void k_main(const float* __restrict__ x,
                                                 const f16x8* __restrict__ packed,
                                                 const float* __restrict__ cn2,
                                                 float* __restrict__ discrete,
                                                 int* __restrict__ bestidx) {
    const int t = threadIdx.x;
    const int L = t & 63;
    const int w = t >> 6;                 // wave = code quarter (ascending codes)
    const int row0 = blockIdx.x * RPB;
    const int lane15 = L & 15;
    const int quad = L >> 4;

    // ---- A fragments: two row groups, exact hi/lo split ----
    const float* xa = x + (size_t)(row0 + lane15) * DDIM + quad * 8;
    const float* xb = xa + 16 * DDIM;
    f16x8 Ah0, Al0, Ah1, Al1, Bh0, Bl0, Bh1, Bl1;
#pragma unroll
    for (int j = 0; j < 8; ++j) {
        float v = xa[j];        _Float16 h = (_Float16)v;
        Ah0[j] = h; Al0[j] = (_Float16)(v - (float)h);
        v = xa[32 + j];         h = (_Float16)v;
        Ah1[j] = h; Al1[j] = (_Float16)(v - (float)h);
        v = xb[j];              h = (_Float16)v;
        Bh0[j] = h; Bl0[j] = (_Float16)(v - (float)h);
        v = xb[32 + j];         h = (_Float16)v;
        Bh1[j] = h; Bl1[j] = (_Float16)(v - (float)h);
    }

    float bvA[4], bvB[4];
    int   biA[4], biB[4];
#pragma unroll
    for (int r = 0; r < 4; ++r) { bvA[r] = bvB[r] = -3.4e38f; biA[r] = biB[r] = 0; }

    const f32x4 zero4 = {0.f, 0.f, 0.f, 0.f};
    const int code0 = w * WCODES;
    const f16x8* pbase = packed + (size_t)(code0 >> 4) * 256 + L;

    // preload tiles 0 (cur) and 1 (nxt): B frags + cn
    f16x8 ch0 = pbase[0], ch1 = pbase[64], cl0 = pbase[128], cl1 = pbase[192];
    float cn = cn2[code0 + lane15];
    const f16x8* p1 = pbase + 256;
    f16x8 nh0 = p1[0], nh1 = p1[64], nl0 = p1[128], nl1 = p1[192];
    float cnn = cn2[code0 + 16 + lane15];

    f32x4* zdst = (f32x4*)(discrete + (size_t)row0 * KCODES);   // 65536 f32x4/block

    for (int i = 0; i < WTILES; ++i) {
        // ---- prefetch tile i+2 (reach ~2 MFMA bursts, covers L2 latency) ----
        const int i2 = (i + 2 < WTILES) ? i + 2 : WTILES - 1;
        const f16x8* pm = pbase + (size_t)i2 * 256;
        f16x8 mh0 = pm[0], mh1 = pm[64], ml0 = pm[128], ml1 = pm[192];
        float cnm = cn2[code0 + i2 * 16 + lane15];

        // ---- NT zero-fill: 2 f32x4 per thread per tile (65536 total/block) ----
        {
            int g = i * 512 + t;
            __builtin_nontemporal_store(zero4, zdst + g);
            __builtin_nontemporal_store(zero4, zdst + g + 256);
        }

        // ---- compute current tile ----
        const int ct = code0 + i * 16;
        f32x4 accA = {-cn, -cn, -cn, -cn};
        f32x4 accB = accA;
        accA = __builtin_amdgcn_mfma_f32_16x16x32_f16(Ah0, ch0, accA, 0, 0, 0);
        accB = __builtin_amdgcn_mfma_f32_16x16x32_f16(Bh0, ch0, accB, 0, 0, 0);
        accA = __builtin_amdgcn_mfma_f32_16x16x32_f16(Ah1, ch1, accA, 0, 0, 0);
        accB = __builtin_amdgcn_mfma_f32_16x16x32_f16(Bh1, ch1, accB, 0, 0, 0);
        accA = __builtin_amdgcn_mfma_f32_16x16x32_f16(Al0, ch0, accA, 0, 0, 0);
        accB = __builtin_amdgcn_mfma_f32_16x16x32_f16(Bl0, ch0, accB, 0, 0, 0);
        accA = __builtin_amdgcn_mfma_f32_16x16x32_f16(Al1, ch1, accA, 0, 0, 0);
        accB = __builtin_amdgcn_mfma_f32_16x16x32_f16(Bl1, ch1, accB, 0, 0, 0);
        accA = __builtin_amdgcn_mfma_f32_16x16x32_f16(Ah0, cl0, accA, 0, 0, 0);
        accB = __builtin_amdgcn_mfma_f32_16x16x32_f16(Bh0, cl0, accB, 0, 0, 0);
        accA = __builtin_amdgcn_mfma_f32_16x16x32_f16(Ah1, cl1, accA, 0, 0, 0);
        accB = __builtin_amdgcn_mfma_f32_16x16x32_f16(Bh1, cl1, accB, 0, 0, 0);
        accA = __builtin_amdgcn_mfma_f32_16x16x32_f16(Al0, cl0, accA, 0, 0, 0);
        accB = __builtin_amdgcn_mfma_f32_16x16x32_f16(Bl0, cl0, accB, 0, 0, 0);
        accA = __builtin_amdgcn_mfma_f32_16x16x32_f16(Al1, cl1, accA, 0, 0, 0);
        accB = __builtin_amdgcn_mfma_f32_16x16x32_f16(Bl1, cl1, accB, 0, 0, 0);

        const int vcode = ct + lane15;
#pragma unroll
        for (int r = 0; r < 4; ++r) {
            if (accA[r] > bvA[r]) { bvA[r] = accA[r]; biA[r] = vcode; }
            if (accB[r] > bvB[r]) { bvB[r] = accB[r]; biB[r] = vcode; }
        }

        // ---- rotate pipeline stages ----
        ch0 = nh0; ch1 = nh1; cl0 = nl0; cl1 = nl1; cn = cnn;
        nh0 = mh0; nh1 = mh1; nl0 = ml0; nl1 = ml1; cnn = cnm;
    }

    // ---- 16-lane butterfly per quad, then cross-wave LDS reduce ----
    __shared__ float rv[RPB][CWAVES + 1];
    __shared__ int   ri[RPB][CWAVES + 1];
#pragma unroll
    for (int r = 0; r < 4; ++r) {
        float vA = bvA[r], vB = bvB[r];
        int  iA = biA[r], iB = biB[r];
#pragma unroll
        for (int m = 1; m < 16; m <<= 1) {
            float oA = __shfl_xor(vA, m, 64); int xA = __shfl_xor(iA, m, 64);
            if (oA > vA || (oA == vA && xA < iA)) { vA = oA; iA = xA; }
            float oB = __shfl_xor(vB, m, 64); int xB = __shfl_xor(iB, m, 64);
            if (oB > vB || (oB == vB && xB < iB)) { vB = oB; iB = xB; }
        }
        if (lane15 == 0) {
            rv[quad * 4 + r][w] = vA;      ri[quad * 4 + r][w] = iA;
            rv[16 + quad * 4 + r][w] = vB; ri[16 + quad * 4 + r][w] = iB;
        }
    }
    __syncthreads();   // drains NT zero stores before the 1.0 write
    if (t < RPB) {
        float bv = rv[t][0];
        int   bi = ri[t][0];
#pragma unroll
        for (int w2 = 1; w2 < CWAVES; ++w2) {  // ascending wave = ascending codes
            float v = rv[t][w2];
            int  id = ri[t][w2];
            if (v > bv || (v == bv && id < bi)) { bv = v; bi = id; }
        }
        int row = row0 + t;
        bestidx[row] = bi;
        discrete[(size_t)row * KCODES + bi] = 1.0f;
    }
}

// ---------------- kernel 2: quantized gather ----------------
__global__ __launch_bounds__(256) void k_finish(const float* __restrict__ cb,
                                                const int* __restrict__ bestidx,
                                                float* __restrict__ quantized) {
    __shared__ int sidx[256];
    const int t = threadIdx.x;
    const int row0 = blockIdx.x * 256;
    sidx[t] = bestidx[row0 + t];
    __syncthreads();
#pragma unroll
    for (int i = 0; i < 16; ++i) {
        int e = i * 256 + t;
        int r = e >> 4, c = e & 15;
        float4 v = *((const float4*)(cb + (size_t)sidx[r] * DDIM) + c);
        *((float4*)(quantized + (size_t)(row0 + r) * DDIM) + c) = v;
    }
}

extern "C" void kernel_launch(void* const* d_in, const int* in_sizes, int n_in,
                              void* d_out, int out_size, void* d_ws, size_t ws_size,
                              hipStream_t stream) {
    const float* x  = (const float*)d_in[0];   // 16*32*32*64
    const float* cb = (const float*)d_in[1];   // 8192*64

    float* discrete  = (float*)d_out;                          // 16384*8192
    float* quantized = (float*)d_out + (size_t)NROWS * KCODES; // 16384*64

    // packed B-fragments (2 MB) live in the quantized output region (4 MB):
    // k_main only reads it; k_finish overwrites quantized afterwards.
    f16x8* packed = (f16x8*)quantized;

    float* cn2     = (float*)d_ws;             // 8192 floats
    int*   bestidx = (int*)(cn2 + KCODES);     // 16384 ints

    k_prep<<<(KCODES / 16) * 64 / 256, 256, 0, stream>>>(cb, packed, cn2);
    k_main<<<NROWS / RPB, CWAVES * 64, 0, stream>>>(x, packed, cn2, discrete, bestidx);
    k_finish<<<NROWS / 256, 256, 0, stream>>>(cb, bestidx, quantized);
}

// Round 13
// 528.791 us; speedup vs baseline: 1.0341x; 1.0042x over previous
//
#include <hip/hip_runtime.h>

// VectorQuantizer: x[16384][64] fp32, codebook[8192][64] fp32
// out = concat(discrete one-hot [16384][8192] fp32, quantized [16384][64] fp32)
// argmin_k ||x-c_k||^2 == argmax_k (x.c_k - 0.5||c_k||^2)
//
// r12 -> r13: fuse the quantized gather into k_main (each block already knows
// its 32 rows' bestidx after the in-block reduce) and drop k_finish entirely.
// packed moves from the quantized output region into d_ws (poison-fill counter
// shows a single 2.16 GB fill dispatch -> ws >= 1.6 GB >> 2 MB needed).
// k_main hot loop identical to r12: RPB=32, 4 waves x 2048 codes, 256 thr,
// __launch_bounds__(256,4) (16 waves/CU), depth-2 register prefetch of
// B-frags + cn2, NT zero-fill interleaved, in-block argmax + one-hot.
// Exact fp32 dots via fp16 hi/lo split, 8 MFMA terms, bit-identical order.

#define NROWS 16384
#define KCODES 8192
#define DDIM 64
#define RPB 32                    // rows per block
#define CWAVES 4                  // waves per block (256 threads)
#define WCODES (KCODES / CWAVES)  // 2048 codes per wave
#define WTILES (WCODES / 16)      // 128 tiles per wave

typedef float    f32x4 __attribute__((ext_vector_type(4)));
typedef _Float16 f16x8 __attribute__((ext_vector_type(8)));

// ---------------- kernel 0: fused pack + cn2 ----------------
// thread (Tg, L): code = Tg*16 + (L&15), k-slice = (L>>4)*8 (+32).
// packed[Tg][frag][lane]: frag 0=hi k0..31, 1=hi k32..63, 2=lo k0..31, 3=lo k32..63.
__global__ __launch_bounds__(256) void k_prep(const float* __restrict__ cb,
                                              f16x8* __restrict__ packed,
                                              float* __restrict__ cn2) {
    int tid = blockIdx.x * 256 + threadIdx.x;   // 0..32767
    int Tg = tid >> 6, L = tid & 63;
    int lane15 = L & 15, quad = L >> 4;
    int code = Tg * 16 + lane15;
    const float* p = cb + (size_t)code * DDIM + quad * 8;
    f16x8 h0, l0, h1, l1;
    float s = 0.f;
#pragma unroll
    for (int j = 0; j < 8; ++j) {
        float v = p[j];
        _Float16 h = (_Float16)v;
        h0[j] = h; l0[j] = (_Float16)(v - (float)h);
        s = fmaf(v, v, s);
        float w = p[32 + j];
        _Float16 h2 = (_Float16)w;
        h1[j] = h2; l1[j] = (_Float16)(w - (float)h2);
        s = fmaf(w, w, s);
    }
    s += __shfl_xor(s, 16, 64);
    s += __shfl_xor(s, 32, 64);
    if (quad == 0) cn2[code] = 0.5f * s;
    f16x8* out = packed + (size_t)Tg * 256 + L;
    out[0]   = h0;
    out[64]  = h1;
    out[128] = l0;
    out[192] = l1;
}

// ---------------- kernel 1: MFMA + argmax + NT zero-fill + one-hot + quantized ----------------
__global__ __launch_bounds__(256, 4) void k_main(const float* __restrict__ x,
                                                 const float* __restrict__ cb,
                                                 const f16x8* __restrict__ packed,
                                                 const float* __restrict__ cn2,
                                                 float* __restrict__ discrete,
                                                 float* __restrict__ quantized) {
    const int t = threadIdx.x;
    const int L = t & 63;
    const int w = t >> 6;                 // wave = code quarter (ascending codes)
    const int row0 = blockIdx.x * RPB;
    const int lane15 = L & 15;
    const int quad = L >> 4;

    // ---- A fragments: two row groups, exact hi/lo split ----
    const float* xa = x + (size_t)(row0 + lane15) * DDIM + quad * 8;
    const float* xb = xa + 16 * DDIM;
    f16x8 Ah0, Al0, Ah1, Al1, Bh0, Bl0, Bh1, Bl1;
#pragma unroll
    for (int j = 0; j < 8; ++j) {
        float v = xa[j];        _Float16 h = (_Float16)v;
        Ah0[j] = h; Al0[j] = (_Float16)(v - (float)h);
        v = xa[32 + j];         h = (_Float16)v;
        Ah1[j] = h; Al1[j] = (_Float16)(v - (float)h);
        v = xb[j];              h = (_Float16)v;
        Bh0[j] = h; Bl0[j] = (_Float16)(v - (float)h);
        v = xb[32 + j];         h = (_Float16)v;
        Bh1[j] = h; Bl1[j] = (_Float16)(v - (float)h);
    }

    float bvA[4], bvB[4];
    int   biA[4], biB[4];
#pragma unroll
    for (int r = 0; r < 4; ++r) { bvA[r] = bvB[r] = -3.4e38f; biA[r] = biB[r] = 0; }

    const f32x4 zero4 = {0.f, 0.f, 0.f, 0.f};
    const int code0 = w * WCODES;
    const f16x8* pbase = packed + (size_t)(code0 >> 4) * 256 + L;

    // preload tiles 0 (cur) and 1 (nxt): B frags + cn
    f16x8 ch0 = pbase[0], ch1 = pbase[64], cl0 = pbase[128], cl1 = pbase[192];
    float cn = cn2[code0 + lane15];
    const f16x8* p1 = pbase + 256;
    f16x8 nh0 = p1[0], nh1 = p1[64], nl0 = p1[128], nl1 = p1[192];
    float cnn = cn2[code0 + 16 + lane15];

    f32x4* zdst = (f32x4*)(discrete + (size_t)row0 * KCODES);   // 65536 f32x4/block

    for (int i = 0; i < WTILES; ++i) {
        // ---- prefetch tile i+2 (reach ~2 MFMA bursts, covers L2 latency) ----
        const int i2 = (i + 2 < WTILES) ? i + 2 : WTILES - 1;
        const f16x8* pm = pbase + (size_t)i2 * 256;
        f16x8 mh0 = pm[0], mh1 = pm[64], ml0 = pm[128], ml1 = pm[192];
        float cnm = cn2[code0 + i2 * 16 + lane15];

        // ---- NT zero-fill: 2 f32x4 per thread per tile (65536 total/block) ----
        {
            int g = i * 512 + t;
            __builtin_nontemporal_store(zero4, zdst + g);
            __builtin_nontemporal_store(zero4, zdst + g + 256);
        }

        // ---- compute current tile ----
        const int ct = code0 + i * 16;
        f32x4 accA = {-cn, -cn, -cn, -cn};
        f32x4 accB = accA;
        accA = __builtin_amdgcn_mfma_f32_16x16x32_f16(Ah0, ch0, accA, 0, 0, 0);
        accB = __builtin_amdgcn_mfma_f32_16x16x32_f16(Bh0, ch0, accB, 0, 0, 0);
        accA = __builtin_amdgcn_mfma_f32_16x16x32_f16(Ah1, ch1, accA, 0, 0, 0);
        accB = __builtin_amdgcn_mfma_f32_16x16x32_f16(Bh1, ch1, accB, 0, 0, 0);
        accA = __builtin_amdgcn_mfma_f32_16x16x32_f16(Al0, ch0, accA, 0, 0, 0);
        accB = __builtin_amdgcn_mfma_f32_16x16x32_f16(Bl0, ch0, accB, 0, 0, 0);
        accA = __builtin_amdgcn_mfma_f32_16x16x32_f16(Al1, ch1, accA, 0, 0, 0);
        accB = __builtin_amdgcn_mfma_f32_16x16x32_f16(Bl1, ch1, accB, 0, 0, 0);
        accA = __builtin_amdgcn_mfma_f32_16x16x32_f16(Ah0, cl0, accA, 0, 0, 0);
        accB = __builtin_amdgcn_mfma_f32_16x16x32_f16(Bh0, cl0, accB, 0, 0, 0);
        accA = __builtin_amdgcn_mfma_f32_16x16x32_f16(Ah1, cl1, accA, 0, 0, 0);
        accB = __builtin_amdgcn_mfma_f32_16x16x32_f16(Bh1, cl1, accB, 0, 0, 0);
        accA = __builtin_amdgcn_mfma_f32_16x16x32_f16(Al0, cl0, accA, 0, 0, 0);
        accB = __builtin_amdgcn_mfma_f32_16x16x32_f16(Bl0, cl0, accB, 0, 0, 0);
        accA = __builtin_amdgcn_mfma_f32_16x16x32_f16(Al1, cl1, accA, 0, 0, 0);
        accB = __builtin_amdgcn_mfma_f32_16x16x32_f16(Bl1, cl1, accB, 0, 0, 0);

        const int vcode = ct + lane15;
#pragma unroll
        for (int r = 0; r < 4; ++r) {
            if (accA[r] > bvA[r]) { bvA[r] = accA[r]; biA[r] = vcode; }
            if (accB[r] > bvB[r]) { bvB[r] = accB[r]; biB[r] = vcode; }
        }

        // ---- rotate pipeline stages ----
        ch0 = nh0; ch1 = nh1; cl0 = nl0; cl1 = nl1; cn = cnn;
        nh0 = mh0; nh1 = mh1; nl0 = ml0; nl1 = ml1; cnn = cnm;
    }

    // ---- 16-lane butterfly per quad, then cross-wave LDS reduce ----
    __shared__ float rv[RPB][CWAVES + 1];
    __shared__ int   ri[RPB][CWAVES + 1];
    __shared__ int   sidx[RPB];
#pragma unroll
    for (int r = 0; r < 4; ++r) {
        float vA = bvA[r], vB = bvB[r];
        int  iA = biA[r], iB = biB[r];
#pragma unroll
        for (int m = 1; m < 16; m <<= 1) {
            float oA = __shfl_xor(vA, m, 64); int xA = __shfl_xor(iA, m, 64);
            if (oA > vA || (oA == vA && xA < iA)) { vA = oA; iA = xA; }
            float oB = __shfl_xor(vB, m, 64); int xB = __shfl_xor(iB, m, 64);
            if (oB > vB || (oB == vB && xB < iB)) { vB = oB; iB = xB; }
        }
        if (lane15 == 0) {
            rv[quad * 4 + r][w] = vA;      ri[quad * 4 + r][w] = iA;
            rv[16 + quad * 4 + r][w] = vB; ri[16 + quad * 4 + r][w] = iB;
        }
    }
    __syncthreads();   // drains NT zero stores before the 1.0 write
    if (t < RPB) {
        float bv = rv[t][0];
        int   bi = ri[t][0];
#pragma unroll
        for (int w2 = 1; w2 < CWAVES; ++w2) {  // ascending wave = ascending codes
            float v = rv[t][w2];
            int  id = ri[t][w2];
            if (v > bv || (v == bv && id < bi)) { bv = v; bi = id; }
        }
        int row = row0 + t;
        sidx[t] = bi;
        discrete[(size_t)row * KCODES + bi] = 1.0f;
    }
    __syncthreads();

    // ---- fused quantized gather: 32 rows x 16 float4, coalesced ----
#pragma unroll
    for (int e = t; e < RPB * 16; e += 256) {
        int r = e >> 4, c = e & 15;
        float4 v = *((const float4*)(cb + (size_t)sidx[r] * DDIM) + c);
        *((float4*)(quantized + (size_t)(row0 + r) * DDIM) + c) = v;
    }
}

extern "C" void kernel_launch(void* const* d_in, const int* in_sizes, int n_in,
                              void* d_out, int out_size, void* d_ws, size_t ws_size,
                              hipStream_t stream) {
    const float* x  = (const float*)d_in[0];   // 16*32*32*64
    const float* cb = (const float*)d_in[1];   // 8192*64

    float* discrete  = (float*)d_out;                          // 16384*8192
    float* quantized = (float*)d_out + (size_t)NROWS * KCODES; // 16384*64

    // workspace layout: cn2 (32 KB) | packed B-frags (2 MB). Poison-fill
    // counters show a single 2.16 GB fill dispatch -> ws_size >= 1.6 GB.
    float* cn2    = (float*)d_ws;              // 8192 floats
    f16x8* packed = (f16x8*)(cn2 + KCODES);    // 2 MB

    k_prep<<<(KCODES / 16) * 64 / 256, 256, 0, stream>>>(cb, packed, cn2);
    k_main<<<NROWS / RPB, CWAVES * 64, 0, stream>>>(x, cb, packed, cn2,
                                                    discrete, quantized);
}